// Round 22
// baseline (136.886 us; speedup 1.0000x reference)
//
#include <hip/hip_runtime.h>

#define BB 8
#define TT 1024
#define DD 512
#define HH 8
#define HS 64

typedef __attribute__((ext_vector_type(8))) short short8;
typedef __attribute__((ext_vector_type(4))) float f32x4;
typedef __attribute__((ext_vector_type(16))) float f32x16;

#if __has_builtin(__builtin_amdgcn_exp2f)
#define EXP2(x) __builtin_amdgcn_exp2f(x)
#else
#define EXP2(x) exp2f(x)
#endif

__device__ __forceinline__ float bf2f(unsigned short u) {
  union { unsigned int i; float f; } v; v.i = ((unsigned int)u) << 16; return v.f;
}
__device__ __forceinline__ unsigned short f2bf(float f) {
  union { float f; unsigned int i; } v; v.f = f;
  unsigned int i = v.i;
  return (unsigned short)((i + 0x7FFFu + ((i >> 16) & 1u)) >> 16);
}
__device__ __forceinline__ unsigned int cvt_pk_bf16(float lo, float hi) {
  unsigned int r;
  asm volatile("v_cvt_pk_bf16_f32 %0, %1, %2" : "=v"(r) : "v"(lo), "v"(hi));
  return r;
}

// ===== Fragment-tiled layouts =====
__device__ __forceinline__ size_t x16(int r, int k) {
  return (size_t)(r >> 4) * 8192 + ((k >> 5) * 512) + (((k >> 3) & 3) * 128) + ((r & 15) * 8) + (k & 7);
}
__device__ __forceinline__ size_t t32_addr(int n, int k) {
  return (size_t)(n >> 5) * 2048 + ((k >> 4) * 512) + (((k >> 3) & 1) * 256) + ((n & 31) * 8) + (k & 7);
}
// V tiles with sigma = swap bits 2<->3 of (m&15): lane's own QK^T regs feed its PV B-frag slots
__device__ __forceinline__ size_t vt_addr(int o, int m) {
  int s15 = (m & 3) | ((m & 4) << 1) | ((m & 8) >> 1);
  return (size_t)(m >> 5) * 2048 + (((m >> 4) & 1) * 1024) + ((o >> 5) * 512) +
         (((s15 >> 3) & 1) * 256) + ((o & 31) * 8) + (s15 & 7);
}

// ---------------- fused prep: y=0 LN(inputs)->x frag16; y=1 pos->frag16; y=2 weight retile ----------------
__global__ __launch_bounds__(256) void prep(const float* __restrict__ in,
                                            const float* __restrict__ pos,
                                            const float* __restrict__ gamma,
                                            const float* __restrict__ beta,
                                            const float* __restrict__ Wq, const float* __restrict__ Wk,
                                            const float* __restrict__ Wv, const float* __restrict__ Wp,
                                            const float* __restrict__ Wo,
                                            unsigned short* __restrict__ x,
                                            unsigned short* __restrict__ p16,
                                            unsigned short* __restrict__ Tq, unsigned short* __restrict__ Tk,
                                            unsigned short* __restrict__ Tv, unsigned short* __restrict__ Tp,
                                            unsigned short* __restrict__ Two) {
  int t = threadIdx.x;
  if (blockIdx.y == 2) {
    int g = blockIdx.x;
    if (g >= 40) return;
    int sel = g >> 3, gg = g & 7;
    if (sel < 4) {
      const float* win = sel == 0 ? Wq : sel == 1 ? Wk : sel == 2 ? Wv : Wp;
      unsigned short* wout = sel == 0 ? Tq : sel == 1 ? Tk : sel == 2 ? Tv : Tp;
      for (int idx = t; idx < 32768; idx += 256) {
        int of = idx >> 13, kk = (idx >> 9) & 15, l4 = (idx >> 7) & 3, l15 = (idx >> 3) & 15, e = idx & 7;
        int o = of * 16 + l15, k = kk * 32 + l4 * 8 + e;
        wout[(size_t)gg * 32768 + idx] = f2bf(win[(size_t)gg * 32768 + k * 64 + o]);
      }
    } else {
      for (int idx = t; idx < 32768; idx += 256) {
        int of = idx >> 13, kk = (idx >> 9) & 15, l4 = (idx >> 7) & 3, l15 = (idx >> 3) & 15, e = idx & 7;
        int i = gg * 64 + of * 16 + l15, k = kk * 32 + l4 * 8 + e;
        Two[(size_t)gg * 32768 + idx] = f2bf(Wo[(size_t)k * 512 + i]);
      }
    }
    return;
  }
  int rt = blockIdx.x;
  int ri = t >> 4, ki = t & 15;
  if (blockIdx.y == 0) {
    const float* rp = in + ((size_t)rt * 16 + ri) * DD + ki * 32;
    float v[32];
#pragma unroll
    for (int j = 0; j < 8; ++j) *(float4*)&v[j * 4] = *(const float4*)(rp + j * 4);
    float s = 0.f;
#pragma unroll
    for (int j = 0; j < 32; ++j) s += v[j];
    s += __shfl_xor(s, 1); s += __shfl_xor(s, 2); s += __shfl_xor(s, 4); s += __shfl_xor(s, 8);
    float mean = s * (1.0f / DD);
    float vs = 0.f;
#pragma unroll
    for (int j = 0; j < 32; ++j) { float d = v[j] - mean; vs += d * d; }
    vs += __shfl_xor(vs, 1); vs += __shfl_xor(vs, 2); vs += __shfl_xor(vs, 4); vs += __shfl_xor(vs, 8);
    float inv = rsqrtf(vs * (1.0f / DD) + 1e-3f);
    size_t base = (size_t)rt * 8192 + ki * 512 + ri * 8;
#pragma unroll
    for (int qg = 0; qg < 4; ++qg) {
      short8 u;
#pragma unroll
      for (int e = 0; e < 8; ++e) {
        int col = ki * 32 + qg * 8 + e;
        u[e] = (short)f2bf((v[qg * 8 + e] - mean) * inv * gamma[col] + beta[col]);
      }
      *(short8*)(x + base + qg * 128) = u;
    }
  } else {
    const float* rp = pos + ((size_t)rt * 16 + ri) * DD + ki * 32;
    size_t base = (size_t)rt * 8192 + ki * 512 + ri * 8;
#pragma unroll
    for (int qg = 0; qg < 4; ++qg) {
      float4 a = *(const float4*)(rp + qg * 8);
      float4 b = *(const float4*)(rp + qg * 8 + 4);
      short8 u;
      u[0] = (short)f2bf(a.x); u[1] = (short)f2bf(a.y); u[2] = (short)f2bf(a.z); u[3] = (short)f2bf(a.w);
      u[4] = (short)f2bf(b.x); u[5] = (short)f2bf(b.y); u[6] = (short)f2bf(b.z); u[7] = (short)f2bf(b.w);
      *(short8*)(p16 + base + qg * 128) = u;
    }
  }
}

#define MF16(a, b, c) __builtin_amdgcn_mfma_f32_16x16x32_bf16(a, b, c, 0, 0, 0)
#define MF32(a, b, c) __builtin_amdgcn_mfma_f32_32x32x16_bf16(a, b, c, 0, 0, 0)

// ---------------- projections, LDS-staged weights: block = 512 rows x 64 cols, 8 waves ----------------
__global__ __launch_bounds__(512) void proj2(const unsigned short* __restrict__ X,
                                             const unsigned short* __restrict__ POS,
                                             const unsigned short* __restrict__ Wtq,
                                             const unsigned short* __restrict__ Wtk,
                                             const unsigned short* __restrict__ Wtv,
                                             const unsigned short* __restrict__ Wtp,
                                             const float* __restrict__ bu,
                                             const float* __restrict__ bv,
                                             unsigned short* __restrict__ QU,
                                             unsigned short* __restrict__ QV,
                                             unsigned short* __restrict__ KT,
                                             unsigned short* __restrict__ VT,
                                             unsigned short* __restrict__ PT) {
  __shared__ __align__(16) unsigned short Wlds[32768];
  int tid = threadIdx.x;
  int w = tid >> 6, l = tid & 63;
  int l15 = l & 15, l4 = l >> 4;
  int rb = blockIdx.x, h = blockIdx.y, sel = blockIdx.z;
  const unsigned short* Wsrc = (sel == 0 ? Wtq : sel == 1 ? Wtk : sel == 2 ? Wtv : Wtp) + (size_t)h * 32768;
  const unsigned short* A = (sel == 3) ? POS : X;
#pragma unroll
  for (int i = 0; i < 8; ++i)
    *(short8*)(Wlds + (tid + i * 512) * 8) = *(const short8*)(Wsrc + (tid + i * 512) * 8);
  __syncthreads();

  int rt0 = rb * 32 + w * 4;
  f32x4 acc[4][4];
#pragma unroll
  for (int j4 = 0; j4 < 4; ++j4)
#pragma unroll
    for (int of = 0; of < 4; ++of) acc[j4][of] = (f32x4){0.f, 0.f, 0.f, 0.f};
  for (int kk = 0; kk < 16; ++kk) {
    short8 a0 = *(const short8*)(A + (size_t)(rt0 + 0) * 8192 + kk * 512 + l * 8);
    short8 a1 = *(const short8*)(A + (size_t)(rt0 + 1) * 8192 + kk * 512 + l * 8);
    short8 a2 = *(const short8*)(A + (size_t)(rt0 + 2) * 8192 + kk * 512 + l * 8);
    short8 a3 = *(const short8*)(A + (size_t)(rt0 + 3) * 8192 + kk * 512 + l * 8);
    const unsigned short* wp = Wlds + kk * 512 + l * 8;
    short8 w0 = *(const short8*)(wp);
    short8 w1 = *(const short8*)(wp + 8192);
    short8 w2 = *(const short8*)(wp + 16384);
    short8 w3 = *(const short8*)(wp + 24576);
    acc[0][0] = MF16(a0, w0, acc[0][0]); acc[0][1] = MF16(a0, w1, acc[0][1]);
    acc[0][2] = MF16(a0, w2, acc[0][2]); acc[0][3] = MF16(a0, w3, acc[0][3]);
    acc[1][0] = MF16(a1, w0, acc[1][0]); acc[1][1] = MF16(a1, w1, acc[1][1]);
    acc[1][2] = MF16(a1, w2, acc[1][2]); acc[1][3] = MF16(a1, w3, acc[1][3]);
    acc[2][0] = MF16(a2, w0, acc[2][0]); acc[2][1] = MF16(a2, w1, acc[2][1]);
    acc[2][2] = MF16(a2, w2, acc[2][2]); acc[2][3] = MF16(a2, w3, acc[2][3]);
    acc[3][0] = MF16(a3, w0, acc[3][0]); acc[3][1] = MF16(a3, w1, acc[3][1]);
    acc[3][2] = MF16(a3, w2, acc[3][2]); acc[3][3] = MF16(a3, w3, acc[3][3]);
  }

  if (sel == 0) {
    const float S = 0.125f * 1.44269504088896f;  // fold 1/sqrt(64) and log2(e)
#pragma unroll
    for (int of = 0; of < 4; ++of) {
      int o = of * 16 + l15;
      float bum = bu[h * HS + o], bvm = bv[h * HS + o];
#pragma unroll
      for (int j4 = 0; j4 < 4; ++j4)
#pragma unroll
        for (int j = 0; j < 4; ++j) {
          int r = (rt0 + j4) * 16 + l4 * 4 + j;
          int b = r >> 10, n = r & 1023;
          size_t bho = ((size_t)b * HH + h) * 65536;
          size_t ta = t32_addr(n, o);
          QU[bho + ta] = f2bf((acc[j4][of][j] + bum) * S);
          QV[bho + ta] = f2bf((acc[j4][of][j] + bvm) * S);
        }
    }
  } else if (sel == 1) {
#pragma unroll
    for (int of = 0; of < 4; ++of) {
      int o = of * 16 + l15;
#pragma unroll
      for (int j4 = 0; j4 < 4; ++j4)
#pragma unroll
        for (int j = 0; j < 4; ++j) {
          int r = (rt0 + j4) * 16 + l4 * 4 + j;
          int b = r >> 10, n = r & 1023;
          KT[((size_t)b * HH + h) * 65536 + t32_addr(n, o)] = f2bf(acc[j4][of][j]);
        }
    }
  } else if (sel == 2) {
#pragma unroll
    for (int of = 0; of < 4; ++of) {
      int o = of * 16 + l15;
#pragma unroll
      for (int j4 = 0; j4 < 4; ++j4)
#pragma unroll
        for (int j = 0; j < 4; ++j) {
          int r = (rt0 + j4) * 16 + l4 * 4 + j;
          int b = r >> 10, m = r & 1023;
          VT[((size_t)b * HH + h) * 65536 + vt_addr(o, m)] = f2bf(acc[j4][of][j]);
        }
    }
  } else {
#pragma unroll
    for (int of = 0; of < 4; ++of) {
      int o = of * 16 + l15;
#pragma unroll
      for (int j4 = 0; j4 < 4; ++j4)
#pragma unroll
        for (int j = 0; j < 4; ++j) {
          int r = (rt0 + j4) * 16 + l4 * 4 + j;
          int b = r >> 10, n = r & 1023;
          PT[((size_t)b * HH + h) * 65536 + t32_addr(n, o)] = f2bf(acc[j4][of][j]);
        }
    }
  }
}

// ---------------- output projection, LDS-staged weights: block = 256 rows x 64 cols (grid 32x8) ----------------
__global__ __launch_bounds__(512) void out2(const unsigned short* __restrict__ A,
                                            const unsigned short* __restrict__ WoTT,
                                            const float* __restrict__ resid,
                                            const float* __restrict__ bias,
                                            float* __restrict__ Out) {
  __shared__ __align__(16) unsigned short Wlds[32768];
  int tid = threadIdx.x;
  int w = tid >> 6, l = tid & 63;
  int l15 = l & 15, l4 = l >> 4;
  int rb = blockIdx.x, cb = blockIdx.y;
  const unsigned short* Wsrc = WoTT + (size_t)cb * 32768;
#pragma unroll
  for (int i = 0; i < 8; ++i)
    *(short8*)(Wlds + (tid + i * 512) * 8) = *(const short8*)(Wsrc + (tid + i * 512) * 8);
  __syncthreads();

  int rt0 = rb * 16 + w * 2;
  f32x4 acc[2][4];
#pragma unroll
  for (int j4 = 0; j4 < 2; ++j4)
#pragma unroll
    for (int of = 0; of < 4; ++of) acc[j4][of] = (f32x4){0.f, 0.f, 0.f, 0.f};
  for (int kk = 0; kk < 16; ++kk) {
    short8 a0 = *(const short8*)(A + (size_t)(rt0 + 0) * 8192 + kk * 512 + l * 8);
    short8 a1 = *(const short8*)(A + (size_t)(rt0 + 1) * 8192 + kk * 512 + l * 8);
    const unsigned short* wp = Wlds + kk * 512 + l * 8;
    short8 w0 = *(const short8*)(wp);
    short8 w1 = *(const short8*)(wp + 8192);
    short8 w2 = *(const short8*)(wp + 16384);
    short8 w3 = *(const short8*)(wp + 24576);
    acc[0][0] = MF16(a0, w0, acc[0][0]); acc[0][1] = MF16(a0, w1, acc[0][1]);
    acc[0][2] = MF16(a0, w2, acc[0][2]); acc[0][3] = MF16(a0, w3, acc[0][3]);
    acc[1][0] = MF16(a1, w0, acc[1][0]); acc[1][1] = MF16(a1, w1, acc[1][1]);
    acc[1][2] = MF16(a1, w2, acc[1][2]); acc[1][3] = MF16(a1, w3, acc[1][3]);
  }
#pragma unroll
  for (int of = 0; of < 4; ++of) {
    int i = cb * 64 + of * 16 + l15;
    float bi = bias[i];
#pragma unroll
    for (int j4 = 0; j4 < 2; ++j4)
#pragma unroll
      for (int j = 0; j < 4; ++j) {
        int r = (rt0 + j4) * 16 + l4 * 4 + j;
        Out[(size_t)r * DD + i] = acc[j4][of][j] + bi + resid[(size_t)r * DD + i];
      }
  }
}

// ------------- fused rel-attention: 32x32 prepass + software-pipelined QK (1-deep, reg-reuse) -------------
#define WLS 1036
__global__ __launch_bounds__(512, 4) void attn_mfma(const unsigned short* __restrict__ QT,
                                                    const unsigned short* __restrict__ QVT,
                                                    const unsigned short* __restrict__ KT,
                                                    const unsigned short* __restrict__ VT,
                                                    const unsigned short* __restrict__ PT,
                                                    unsigned short* __restrict__ pre) {
  int i = blockIdx.x;
  int slot = i >> 3;
  int p = (i & 7) * 8 + (slot >> 5);
  int nb = slot & 31;
  int b = p >> 3, h = p & 7;
  int n0 = nb * 32;
  __shared__ __align__(16) unsigned short Wl[34][WLS];
  int tid = threadIdx.x;
  int w = tid >> 6, l = tid & 63;
  int l31 = l & 31, hi = l >> 5;
  size_t bh = ((size_t)b * HH + h) * 65536;
  const unsigned short* QTb = QT  + bh;
  const unsigned short* QVb = QVT + bh;
  const unsigned short* KTb = KT  + bh;
  const unsigned short* PTb = PT  + bh;
  const unsigned short* VTb = VT  + bh;

  if (tid < 32) {
    int m = n0 + tid + 1;
    if (m <= TT - 1) Wl[tid][m] = 0;
  }
  // ---- prepass rows 0..31 via 32x32 MFMA; single-store scatter (each bd -> exactly one slot) ----
  {
    const unsigned short* aq = QVb + (size_t)nb * 2048 + l * 8;  // A = QV rows n0..n0+31
    short8 a0 = *(const short8*)(aq);
    short8 a1 = *(const short8*)(aq + 512);
    short8 a2 = *(const short8*)(aq + 1024);
    short8 a3 = *(const short8*)(aq + 1536);
#pragma unroll
    for (int cg = 0; cg < 4; ++cg) {
      int ct = w + 8 * cg;
      const unsigned short* bp = PTb + (size_t)ct * 2048 + l * 8;  // B = P cols ct*32..+31
      f32x16 acc = {};
      acc = MF32(a0, *(const short8*)(bp),        acc);
      acc = MF32(a1, *(const short8*)(bp + 512),  acc);
      acc = MF32(a2, *(const short8*)(bp + 1024), acc);
      acc = MF32(a3, *(const short8*)(bp + 1536), acc);
      int base = ct * 32 + l31 + n0;
#pragma unroll
      for (int i2 = 0; i2 < 16; ++i2) {
        int rr = (i2 & 3) + 8 * (i2 >> 2) + 4 * hi;
        int t = base + rr;
        bool below = (t >= TT - 1);
        int row = below ? rr : (rr - 1);
        int col = below ? (t - (TT - 1)) : (t + 1);
        if (row >= 0) Wl[row][col] = f2bf(acc[i2]);
      }
    }
  }
  // ---- row 32 (serves row 31's above-diag tail): only live col-tiles (c <= 990 - n0) ----
  if (n0 + 32 < TT) {
    const unsigned short* aq = QVb + (size_t)(nb + 1) * 2048 + l * 8;  // A = QV rows n0+32..n0+63
    short8 a0 = *(const short8*)(aq);
    short8 a1 = *(const short8*)(aq + 512);
    short8 a2 = *(const short8*)(aq + 1024);
    short8 a3 = *(const short8*)(aq + 1536);
    for (int ct = w; ct * 32 <= 990 - n0; ct += 8) {
      const unsigned short* bp = PTb + (size_t)ct * 2048 + l * 8;
      f32x16 acc = {};
      acc = MF32(a0, *(const short8*)(bp),        acc);
      acc = MF32(a1, *(const short8*)(bp + 512),  acc);
      acc = MF32(a2, *(const short8*)(bp + 1024), acc);
      acc = MF32(a3, *(const short8*)(bp + 1536), acc);
      if (hi == 0) {                       // reg 0, hi==0 holds row n0+32
        int m2 = ct * 32 + l31 + n0 + 33;
        if (m2 <= TT - 1) Wl[31][m2] = f2bf(acc[0]);
      }
    }
  }
  __syncthreads();

  const unsigned short* qtb = QTb + (size_t)nb * 2048 + l * 8;
  short8 qb0 = *(const short8*)(qtb);
  short8 qb1 = *(const short8*)(qtb + 512);
  short8 qb2 = *(const short8*)(qtb + 1024);
  short8 qb3 = *(const short8*)(qtb + 1536);
  f32x16 Oa0 = {}, Oa1 = {};
  float run_l = 0.f;   // lane-local half-row sum; cross-half combine deferred to epilogue

  // pipeline stage 0: chunk-0 scores computed BEFORE the loop
  f32x16 sc;
  {
    const unsigned short* ktb = KTb + (size_t)w * 2048 + l * 8;
    short8 k0 = *(const short8*)(ktb);
    short8 k1 = *(const short8*)(ktb + 512);
    short8 k2 = *(const short8*)(ktb + 1024);
    short8 k3 = *(const short8*)(ktb + 1536);
    int m0 = w * 32;
#pragma unroll
    for (int g = 0; g < 4; ++g) {
      ushort4 bd4 = *(const ushort4*)&Wl[l31][m0 + 8 * g + 4 * hi];
      sc[4 * g + 0] = bf2f(bd4.x);
      sc[4 * g + 1] = bf2f(bd4.y);
      sc[4 * g + 2] = bf2f(bd4.z);
      sc[4 * g + 3] = bf2f(bd4.w);
    }
    sc = MF32(k0, qb0, sc);
    sc = MF32(k1, qb1, sc);
    sc = MF32(k2, qb2, sc);
    sc = MF32(k3, qb3, sc);
  }

#pragma unroll 1
  for (int ci = 0; ci < 4; ++ci) {
    int mt = ci * 8 + w;
    // V loads for current chunk (early; consumed after exp2/pack)
    const unsigned short* vtb = VTb + (size_t)mt * 2048 + l * 8;
    short8 vv0 = *(const short8*)(vtb);
    short8 vv1 = *(const short8*)(vtb + 1024);
    short8 vv2 = *(const short8*)(vtb + 512);
    short8 vv3 = *(const short8*)(vtb + 1536);
    // next chunk's K loads (issued before the VALU phase)
    short8 kn0, kn1, kn2, kn3;
    if (ci < 3) {
      const unsigned short* kn = KTb + (size_t)(mt + 8) * 2048 + l * 8;
      kn0 = *(const short8*)(kn);
      kn1 = *(const short8*)(kn + 512);
      kn2 = *(const short8*)(kn + 1024);
      kn3 = *(const short8*)(kn + 1536);
    }
    // finish current chunk's softmax numerators
#pragma unroll
    for (int i2 = 0; i2 < 16; ++i2) { sc[i2] = EXP2(sc[i2]); run_l += sc[i2]; }
    short8 bp0, bp1;
    {
      unsigned int* u = (unsigned int*)&bp0;
      u[0] = cvt_pk_bf16(sc[0], sc[1]);
      u[1] = cvt_pk_bf16(sc[2], sc[3]);
      u[2] = cvt_pk_bf16(sc[4], sc[5]);
      u[3] = cvt_pk_bf16(sc[6], sc[7]);
      unsigned int* v2 = (unsigned int*)&bp1;
      v2[0] = cvt_pk_bf16(sc[8], sc[9]);
      v2[1] = cvt_pk_bf16(sc[10], sc[11]);
      v2[2] = cvt_pk_bf16(sc[12], sc[13]);
      v2[3] = cvt_pk_bf16(sc[14], sc[15]);
    }
    // sc is dead after pack -> issue NEXT chunk's BD + QK into it, ahead of PV.
    // QK(i+1) overlaps PV(i) in the MFMA pipe; next iteration starts directly at exp2.
    if (ci < 3) {
      int m0n = (mt + 8) * 32;
#pragma unroll
      for (int g = 0; g < 4; ++g) {
        ushort4 bd4 = *(const ushort4*)&Wl[l31][m0n + 8 * g + 4 * hi];
        sc[4 * g + 0] = bf2f(bd4.x);
        sc[4 * g + 1] = bf2f(bd4.y);
        sc[4 * g + 2] = bf2f(bd4.z);
        sc[4 * g + 3] = bf2f(bd4.w);
      }
      sc = MF32(kn0, qb0, sc);
      sc = MF32(kn1, qb1, sc);
      sc = MF32(kn2, qb2, sc);
      sc = MF32(kn3, qb3, sc);
    }
    // PV for current chunk (V rows pre-permuted by sigma in vt_addr)
    Oa0 = MF32(vv0, bp0, Oa0);
    Oa0 = MF32(vv1, bp1, Oa0);
    Oa1 = MF32(vv2, bp0, Oa1);
    Oa1 = MF32(vv3, bp1, Oa1);
  }
  // deferred cross-half combine (halves accumulate independently; one shfl total)
  run_l += __shfl_xor(run_l, 32);

  __syncthreads();
  float* WLf = (float*)&Wl[0][0];
  float* myO = WLf + w * 2176;
#pragma unroll
  for (int i2 = 0; i2 < 16; ++i2) {
    int o0 = (i2 & 3) + 8 * (i2 >> 2) + 4 * hi;
    myO[o0 * 33 + l31]        = Oa0[i2];
    myO[(o0 + 32) * 33 + l31] = Oa1[i2];
  }
  if (l < 32) myO[2112 + l] = run_l;
  __syncthreads();
#pragma unroll
  for (int q4 = 0; q4 < 4; ++q4) {
    int q = w * 4 + q4;
    float denom = 0.f, val = 0.f;
#pragma unroll
    for (int w2 = 0; w2 < 8; ++w2) {
      denom += WLf[w2 * 2176 + 2112 + q];
      val   += WLf[w2 * 2176 + l * 33 + q];
    }
    pre[x16(b * TT + n0 + q, h * HS + l)] = f2bf(val / denom);
  }
}

extern "C" void kernel_launch(void* const* d_in, const int* in_sizes, int n_in,
                              void* d_out, int out_size, void* d_ws, size_t ws_size,
                              hipStream_t stream) {
  const float* inputs = (const float*)d_in[0];
  const float* pos    = (const float*)d_in[1];
  const float* gamma  = (const float*)d_in[2];
  const float* beta   = (const float*)d_in[3];
  const float* Wq = (const float*)d_in[4];
  const float* Wk = (const float*)d_in[5];
  const float* Wv = (const float*)d_in[6];
  const float* Wp = (const float*)d_in[7];
  const float* bu = (const float*)d_in[8];
  const float* bv = (const float*)d_in[9];
  const float* Wo = (const float*)d_in[10];
  const float* bo = (const float*)d_in[11];
  float* out = (float*)d_out;
  unsigned short* w16 = (unsigned short*)d_ws;

  const size_t T2 = (size_t)BB * TT * DD;
  unsigned short* x_bf  = w16;
  unsigned short* pre_b = x_bf  + T2;
  unsigned short* QUp   = pre_b + T2;
  unsigned short* QVp   = QUp   + T2;
  unsigned short* Kp    = QVp   + T2;
  unsigned short* Vtp   = Kp    + T2;
  unsigned short* Pp    = Vtp   + T2;
  unsigned short* Pos16 = Pp    + T2;
  unsigned short* WtQ   = Pos16 + T2;
  unsigned short* WtK   = WtQ + 262144;
  unsigned short* WtV   = WtK + 262144;
  unsigned short* WtP   = WtV + 262144;
  unsigned short* WoTT  = WtP + 262144;

  prep<<<dim3(512, 3), dim3(256), 0, stream>>>(inputs, pos, gamma, beta, Wq, Wk, Wv, Wp, Wo,
                                               x_bf, Pos16, WtQ, WtK, WtV, WtP, WoTT);
  proj2<<<dim3(16, 8, 4), dim3(512), 0, stream>>>(x_bf, Pos16, WtQ, WtK, WtV, WtP, bu, bv,
                                                  QUp, QVp, Kp, Vtp, Pp);
  attn_mfma<<<dim3(2048), dim3(512), 0, stream>>>(QUp, QVp, Kp, Vtp, Pp, pre_b);
  out2<<<dim3(32, 8), dim3(512), 0, stream>>>(pre_b, WoTT, inputs, bo, out);
}

// Round 23
// 131.613 us; speedup vs baseline: 1.0401x; 1.0401x over previous
//
#include <hip/hip_runtime.h>

#define BB 8
#define TT 1024
#define DD 512
#define HH 8
#define HS 64

typedef __attribute__((ext_vector_type(8))) short short8;
typedef __attribute__((ext_vector_type(4))) float f32x4;
typedef __attribute__((ext_vector_type(16))) float f32x16;

#if __has_builtin(__builtin_amdgcn_exp2f)
#define EXP2(x) __builtin_amdgcn_exp2f(x)
#else
#define EXP2(x) exp2f(x)
#endif

__device__ __forceinline__ float bf2f(unsigned short u) {
  union { unsigned int i; float f; } v; v.i = ((unsigned int)u) << 16; return v.f;
}
__device__ __forceinline__ unsigned short f2bf(float f) {
  union { float f; unsigned int i; } v; v.f = f;
  unsigned int i = v.i;
  return (unsigned short)((i + 0x7FFFu + ((i >> 16) & 1u)) >> 16);
}
__device__ __forceinline__ unsigned int cvt_pk_bf16(float lo, float hi) {
  unsigned int r;
  asm volatile("v_cvt_pk_bf16_f32 %0, %1, %2" : "=v"(r) : "v"(lo), "v"(hi));
  return r;
}

// ===== Fragment-tiled layouts =====
__device__ __forceinline__ size_t x16(int r, int k) {
  return (size_t)(r >> 4) * 8192 + ((k >> 5) * 512) + (((k >> 3) & 3) * 128) + ((r & 15) * 8) + (k & 7);
}
__device__ __forceinline__ size_t t32_addr(int n, int k) {
  return (size_t)(n >> 5) * 2048 + ((k >> 4) * 512) + (((k >> 3) & 1) * 256) + ((n & 31) * 8) + (k & 7);
}
// V tiles with sigma = swap bits 2<->3 of (m&15): lane's own QK^T regs feed its PV B-frag slots
__device__ __forceinline__ size_t vt_addr(int o, int m) {
  int s15 = (m & 3) | ((m & 4) << 1) | ((m & 8) >> 1);
  return (size_t)(m >> 5) * 2048 + (((m >> 4) & 1) * 1024) + ((o >> 5) * 512) +
         (((s15 >> 3) & 1) * 256) + ((o & 31) * 8) + (s15 & 7);
}

// ---------------- fused prep: y=0 LN(inputs)->x frag16; y=1 pos->frag16; y=2 weight retile ----------------
__global__ __launch_bounds__(256) void prep(const float* __restrict__ in,
                                            const float* __restrict__ pos,
                                            const float* __restrict__ gamma,
                                            const float* __restrict__ beta,
                                            const float* __restrict__ Wq, const float* __restrict__ Wk,
                                            const float* __restrict__ Wv, const float* __restrict__ Wp,
                                            const float* __restrict__ Wo,
                                            unsigned short* __restrict__ x,
                                            unsigned short* __restrict__ p16,
                                            unsigned short* __restrict__ Tq, unsigned short* __restrict__ Tk,
                                            unsigned short* __restrict__ Tv, unsigned short* __restrict__ Tp,
                                            unsigned short* __restrict__ Two) {
  int t = threadIdx.x;
  if (blockIdx.y == 2) {
    int g = blockIdx.x;
    if (g >= 40) return;
    int sel = g >> 3, gg = g & 7;
    if (sel < 4) {
      const float* win = sel == 0 ? Wq : sel == 1 ? Wk : sel == 2 ? Wv : Wp;
      unsigned short* wout = sel == 0 ? Tq : sel == 1 ? Tk : sel == 2 ? Tv : Tp;
      for (int idx = t; idx < 32768; idx += 256) {
        int of = idx >> 13, kk = (idx >> 9) & 15, l4 = (idx >> 7) & 3, l15 = (idx >> 3) & 15, e = idx & 7;
        int o = of * 16 + l15, k = kk * 32 + l4 * 8 + e;
        wout[(size_t)gg * 32768 + idx] = f2bf(win[(size_t)gg * 32768 + k * 64 + o]);
      }
    } else {
      for (int idx = t; idx < 32768; idx += 256) {
        int of = idx >> 13, kk = (idx >> 9) & 15, l4 = (idx >> 7) & 3, l15 = (idx >> 3) & 15, e = idx & 7;
        int i = gg * 64 + of * 16 + l15, k = kk * 32 + l4 * 8 + e;
        Two[(size_t)gg * 32768 + idx] = f2bf(Wo[(size_t)k * 512 + i]);
      }
    }
    return;
  }
  int rt = blockIdx.x;
  int ri = t >> 4, ki = t & 15;
  if (blockIdx.y == 0) {
    const float* rp = in + ((size_t)rt * 16 + ri) * DD + ki * 32;
    float v[32];
#pragma unroll
    for (int j = 0; j < 8; ++j) *(float4*)&v[j * 4] = *(const float4*)(rp + j * 4);
    float s = 0.f;
#pragma unroll
    for (int j = 0; j < 32; ++j) s += v[j];
    s += __shfl_xor(s, 1); s += __shfl_xor(s, 2); s += __shfl_xor(s, 4); s += __shfl_xor(s, 8);
    float mean = s * (1.0f / DD);
    float vs = 0.f;
#pragma unroll
    for (int j = 0; j < 32; ++j) { float d = v[j] - mean; vs += d * d; }
    vs += __shfl_xor(vs, 1); vs += __shfl_xor(vs, 2); vs += __shfl_xor(vs, 4); vs += __shfl_xor(vs, 8);
    float inv = rsqrtf(vs * (1.0f / DD) + 1e-3f);
    size_t base = (size_t)rt * 8192 + ki * 512 + ri * 8;
#pragma unroll
    for (int qg = 0; qg < 4; ++qg) {
      short8 u;
#pragma unroll
      for (int e = 0; e < 8; ++e) {
        int col = ki * 32 + qg * 8 + e;
        u[e] = (short)f2bf((v[qg * 8 + e] - mean) * inv * gamma[col] + beta[col]);
      }
      *(short8*)(x + base + qg * 128) = u;
    }
  } else {
    const float* rp = pos + ((size_t)rt * 16 + ri) * DD + ki * 32;
    size_t base = (size_t)rt * 8192 + ki * 512 + ri * 8;
#pragma unroll
    for (int qg = 0; qg < 4; ++qg) {
      float4 a = *(const float4*)(rp + qg * 8);
      float4 b = *(const float4*)(rp + qg * 8 + 4);
      short8 u;
      u[0] = (short)f2bf(a.x); u[1] = (short)f2bf(a.y); u[2] = (short)f2bf(a.z); u[3] = (short)f2bf(a.w);
      u[4] = (short)f2bf(b.x); u[5] = (short)f2bf(b.y); u[6] = (short)f2bf(b.z); u[7] = (short)f2bf(b.w);
      *(short8*)(p16 + base + qg * 128) = u;
    }
  }
}

#define MF16(a, b, c) __builtin_amdgcn_mfma_f32_16x16x32_bf16(a, b, c, 0, 0, 0)
#define MF32(a, b, c) __builtin_amdgcn_mfma_f32_32x32x16_bf16(a, b, c, 0, 0, 0)

// ---------------- projections, LDS-staged weights: block = 512 rows x 64 cols, 8 waves ----------------
__global__ __launch_bounds__(512) void proj2(const unsigned short* __restrict__ X,
                                             const unsigned short* __restrict__ POS,
                                             const unsigned short* __restrict__ Wtq,
                                             const unsigned short* __restrict__ Wtk,
                                             const unsigned short* __restrict__ Wtv,
                                             const unsigned short* __restrict__ Wtp,
                                             const float* __restrict__ bu,
                                             const float* __restrict__ bv,
                                             unsigned short* __restrict__ QU,
                                             unsigned short* __restrict__ QV,
                                             unsigned short* __restrict__ KT,
                                             unsigned short* __restrict__ VT,
                                             unsigned short* __restrict__ PT) {
  __shared__ __align__(16) unsigned short Wlds[32768];
  int tid = threadIdx.x;
  int w = tid >> 6, l = tid & 63;
  int l15 = l & 15, l4 = l >> 4;
  int rb = blockIdx.x, h = blockIdx.y, sel = blockIdx.z;
  const unsigned short* Wsrc = (sel == 0 ? Wtq : sel == 1 ? Wtk : sel == 2 ? Wtv : Wtp) + (size_t)h * 32768;
  const unsigned short* A = (sel == 3) ? POS : X;
#pragma unroll
  for (int i = 0; i < 8; ++i)
    *(short8*)(Wlds + (tid + i * 512) * 8) = *(const short8*)(Wsrc + (tid + i * 512) * 8);
  __syncthreads();

  int rt0 = rb * 32 + w * 4;
  f32x4 acc[4][4];
#pragma unroll
  for (int j4 = 0; j4 < 4; ++j4)
#pragma unroll
    for (int of = 0; of < 4; ++of) acc[j4][of] = (f32x4){0.f, 0.f, 0.f, 0.f};
  for (int kk = 0; kk < 16; ++kk) {
    short8 a0 = *(const short8*)(A + (size_t)(rt0 + 0) * 8192 + kk * 512 + l * 8);
    short8 a1 = *(const short8*)(A + (size_t)(rt0 + 1) * 8192 + kk * 512 + l * 8);
    short8 a2 = *(const short8*)(A + (size_t)(rt0 + 2) * 8192 + kk * 512 + l * 8);
    short8 a3 = *(const short8*)(A + (size_t)(rt0 + 3) * 8192 + kk * 512 + l * 8);
    const unsigned short* wp = Wlds + kk * 512 + l * 8;
    short8 w0 = *(const short8*)(wp);
    short8 w1 = *(const short8*)(wp + 8192);
    short8 w2 = *(const short8*)(wp + 16384);
    short8 w3 = *(const short8*)(wp + 24576);
    acc[0][0] = MF16(a0, w0, acc[0][0]); acc[0][1] = MF16(a0, w1, acc[0][1]);
    acc[0][2] = MF16(a0, w2, acc[0][2]); acc[0][3] = MF16(a0, w3, acc[0][3]);
    acc[1][0] = MF16(a1, w0, acc[1][0]); acc[1][1] = MF16(a1, w1, acc[1][1]);
    acc[1][2] = MF16(a1, w2, acc[1][2]); acc[1][3] = MF16(a1, w3, acc[1][3]);
    acc[2][0] = MF16(a2, w0, acc[2][0]); acc[2][1] = MF16(a2, w1, acc[2][1]);
    acc[2][2] = MF16(a2, w2, acc[2][2]); acc[2][3] = MF16(a2, w3, acc[2][3]);
    acc[3][0] = MF16(a3, w0, acc[3][0]); acc[3][1] = MF16(a3, w1, acc[3][1]);
    acc[3][2] = MF16(a3, w2, acc[3][2]); acc[3][3] = MF16(a3, w3, acc[3][3]);
  }

  if (sel == 0) {
    const float S = 0.125f * 1.44269504088896f;  // fold 1/sqrt(64) and log2(e)
#pragma unroll
    for (int of = 0; of < 4; ++of) {
      int o = of * 16 + l15;
      float bum = bu[h * HS + o], bvm = bv[h * HS + o];
#pragma unroll
      for (int j4 = 0; j4 < 4; ++j4)
#pragma unroll
        for (int j = 0; j < 4; ++j) {
          int r = (rt0 + j4) * 16 + l4 * 4 + j;
          int b = r >> 10, n = r & 1023;
          size_t bho = ((size_t)b * HH + h) * 65536;
          size_t ta = t32_addr(n, o);
          QU[bho + ta] = f2bf((acc[j4][of][j] + bum) * S);
          QV[bho + ta] = f2bf((acc[j4][of][j] + bvm) * S);
        }
    }
  } else if (sel == 1) {
#pragma unroll
    for (int of = 0; of < 4; ++of) {
      int o = of * 16 + l15;
#pragma unroll
      for (int j4 = 0; j4 < 4; ++j4)
#pragma unroll
        for (int j = 0; j < 4; ++j) {
          int r = (rt0 + j4) * 16 + l4 * 4 + j;
          int b = r >> 10, n = r & 1023;
          KT[((size_t)b * HH + h) * 65536 + t32_addr(n, o)] = f2bf(acc[j4][of][j]);
        }
    }
  } else if (sel == 2) {
#pragma unroll
    for (int of = 0; of < 4; ++of) {
      int o = of * 16 + l15;
#pragma unroll
      for (int j4 = 0; j4 < 4; ++j4)
#pragma unroll
        for (int j = 0; j < 4; ++j) {
          int r = (rt0 + j4) * 16 + l4 * 4 + j;
          int b = r >> 10, m = r & 1023;
          VT[((size_t)b * HH + h) * 65536 + vt_addr(o, m)] = f2bf(acc[j4][of][j]);
        }
    }
  } else {
#pragma unroll
    for (int of = 0; of < 4; ++of) {
      int o = of * 16 + l15;
#pragma unroll
      for (int j4 = 0; j4 < 4; ++j4)
#pragma unroll
        for (int j = 0; j < 4; ++j) {
          int r = (rt0 + j4) * 16 + l4 * 4 + j;
          int b = r >> 10, n = r & 1023;
          PT[((size_t)b * HH + h) * 65536 + t32_addr(n, o)] = f2bf(acc[j4][of][j]);
        }
    }
  }
}

// ---------------- output projection, LDS-staged weights: block = 256 rows x 64 cols (grid 32x8) ----------------
__global__ __launch_bounds__(512) void out2(const unsigned short* __restrict__ A,
                                            const unsigned short* __restrict__ WoTT,
                                            const float* __restrict__ resid,
                                            const float* __restrict__ bias,
                                            float* __restrict__ Out) {
  __shared__ __align__(16) unsigned short Wlds[32768];
  int tid = threadIdx.x;
  int w = tid >> 6, l = tid & 63;
  int l15 = l & 15, l4 = l >> 4;
  int rb = blockIdx.x, cb = blockIdx.y;
  const unsigned short* Wsrc = WoTT + (size_t)cb * 32768;
#pragma unroll
  for (int i = 0; i < 8; ++i)
    *(short8*)(Wlds + (tid + i * 512) * 8) = *(const short8*)(Wsrc + (tid + i * 512) * 8);
  __syncthreads();

  int rt0 = rb * 16 + w * 2;
  f32x4 acc[2][4];
#pragma unroll
  for (int j4 = 0; j4 < 2; ++j4)
#pragma unroll
    for (int of = 0; of < 4; ++of) acc[j4][of] = (f32x4){0.f, 0.f, 0.f, 0.f};
  for (int kk = 0; kk < 16; ++kk) {
    short8 a0 = *(const short8*)(A + (size_t)(rt0 + 0) * 8192 + kk * 512 + l * 8);
    short8 a1 = *(const short8*)(A + (size_t)(rt0 + 1) * 8192 + kk * 512 + l * 8);
    const unsigned short* wp = Wlds + kk * 512 + l * 8;
    short8 w0 = *(const short8*)(wp);
    short8 w1 = *(const short8*)(wp + 8192);
    short8 w2 = *(const short8*)(wp + 16384);
    short8 w3 = *(const short8*)(wp + 24576);
    acc[0][0] = MF16(a0, w0, acc[0][0]); acc[0][1] = MF16(a0, w1, acc[0][1]);
    acc[0][2] = MF16(a0, w2, acc[0][2]); acc[0][3] = MF16(a0, w3, acc[0][3]);
    acc[1][0] = MF16(a1, w0, acc[1][0]); acc[1][1] = MF16(a1, w1, acc[1][1]);
    acc[1][2] = MF16(a1, w2, acc[1][2]); acc[1][3] = MF16(a1, w3, acc[1][3]);
  }
#pragma unroll
  for (int of = 0; of < 4; ++of) {
    int i = cb * 64 + of * 16 + l15;
    float bi = bias[i];
#pragma unroll
    for (int j4 = 0; j4 < 2; ++j4)
#pragma unroll
      for (int j = 0; j < 4; ++j) {
        int r = (rt0 + j4) * 16 + l4 * 4 + j;
        Out[(size_t)r * DD + i] = acc[j4][of][j] + bi + resid[(size_t)r * DD + i];
      }
  }
}

// ------------- fused rel-attention: 32x32 prepass (single-store scatter) + K-prefetch main loop -------------
#define WLS 1036
__global__ __launch_bounds__(512, 4) void attn_mfma(const unsigned short* __restrict__ QT,
                                                    const unsigned short* __restrict__ QVT,
                                                    const unsigned short* __restrict__ KT,
                                                    const unsigned short* __restrict__ VT,
                                                    const unsigned short* __restrict__ PT,
                                                    unsigned short* __restrict__ pre) {
  int i = blockIdx.x;
  int slot = i >> 3;
  int p = (i & 7) * 8 + (slot >> 5);
  int nb = slot & 31;
  int b = p >> 3, h = p & 7;
  int n0 = nb * 32;
  __shared__ __align__(16) unsigned short Wl[34][WLS];
  int tid = threadIdx.x;
  int w = tid >> 6, l = tid & 63;
  int l31 = l & 31, hi = l >> 5;
  size_t bh = ((size_t)b * HH + h) * 65536;
  const unsigned short* QTb = QT  + bh;
  const unsigned short* QVb = QVT + bh;
  const unsigned short* KTb = KT  + bh;
  const unsigned short* PTb = PT  + bh;
  const unsigned short* VTb = VT  + bh;

  if (tid < 32) {
    int m = n0 + tid + 1;
    if (m <= TT - 1) Wl[tid][m] = 0;
  }
  // ---- prepass rows 0..31 via 32x32 MFMA: wave w covers col-tiles {w, w+8, w+16, w+24} ----
  {
    const unsigned short* aq = QVb + (size_t)nb * 2048 + l * 8;  // A = QV rows n0..n0+31
    short8 a0 = *(const short8*)(aq);
    short8 a1 = *(const short8*)(aq + 512);
    short8 a2 = *(const short8*)(aq + 1024);
    short8 a3 = *(const short8*)(aq + 1536);
#pragma unroll
    for (int cg = 0; cg < 4; ++cg) {
      int ct = w + 8 * cg;
      const unsigned short* bp = PTb + (size_t)ct * 2048 + l * 8;  // B = P cols ct*32..+31
      f32x16 acc = {};
      acc = MF32(a0, *(const short8*)(bp),        acc);
      acc = MF32(a1, *(const short8*)(bp + 512),  acc);
      acc = MF32(a2, *(const short8*)(bp + 1024), acc);
      acc = MF32(a3, *(const short8*)(bp + 1536), acc);
      int base = ct * 32 + l31 + n0;
#pragma unroll
      for (int i2 = 0; i2 < 16; ++i2) {
        int rr = (i2 & 3) + 8 * (i2 >> 2) + 4 * hi;
        int t = base + rr;
        bool below = (t >= TT - 1);
        int row = below ? rr : (rr - 1);
        int col = below ? (t - (TT - 1)) : (t + 1);
        if (row >= 0) Wl[row][col] = f2bf(acc[i2]);
      }
    }
  }
  // ---- row 32 (serves row 31's above-diag tail): only live col-tiles (c <= 990 - n0) ----
  if (n0 + 32 < TT) {
    const unsigned short* aq = QVb + (size_t)(nb + 1) * 2048 + l * 8;  // A = QV rows n0+32..n0+63
    short8 a0 = *(const short8*)(aq);
    short8 a1 = *(const short8*)(aq + 512);
    short8 a2 = *(const short8*)(aq + 1024);
    short8 a3 = *(const short8*)(aq + 1536);
    for (int ct = w; ct * 32 <= 990 - n0; ct += 8) {
      const unsigned short* bp = PTb + (size_t)ct * 2048 + l * 8;
      f32x16 acc = {};
      acc = MF32(a0, *(const short8*)(bp),        acc);
      acc = MF32(a1, *(const short8*)(bp + 512),  acc);
      acc = MF32(a2, *(const short8*)(bp + 1024), acc);
      acc = MF32(a3, *(const short8*)(bp + 1536), acc);
      if (hi == 0) {                       // reg 0, hi==0 holds row n0+32
        int m2 = ct * 32 + l31 + n0 + 33;
        if (m2 <= TT - 1) Wl[31][m2] = f2bf(acc[0]);
      }
    }
  }
  __syncthreads();

  const unsigned short* qtb = QTb + (size_t)nb * 2048 + l * 8;
  short8 qb0 = *(const short8*)(qtb);
  short8 qb1 = *(const short8*)(qtb + 512);
  short8 qb2 = *(const short8*)(qtb + 1024);
  short8 qb3 = *(const short8*)(qtb + 1536);
  f32x16 Oa0 = {}, Oa1 = {};
  float run_l = 0.f;

  // chunk-0 K fragments preloaded (manual 1-deep rotation)
  short8 kc0, kc1, kc2, kc3;
  {
    const unsigned short* ktb = KTb + (size_t)w * 2048 + l * 8;
    kc0 = *(const short8*)(ktb);
    kc1 = *(const short8*)(ktb + 512);
    kc2 = *(const short8*)(ktb + 1024);
    kc3 = *(const short8*)(ktb + 1536);
  }

#pragma unroll 1
  for (int ci = 0; ci < 4; ++ci) {
    int mt = ci * 8 + w;
    int m0 = mt * 32;
    // issue current chunk's V loads EARLY (consumed ~300cy later, after QK+exp2)
    const unsigned short* vtb = VTb + (size_t)mt * 2048 + l * 8;
    short8 vv0 = *(const short8*)(vtb);
    short8 vv1 = *(const short8*)(vtb + 1024);
    short8 vv2 = *(const short8*)(vtb + 512);
    short8 vv3 = *(const short8*)(vtb + 1536);
    // BD rides the QK^T MFMA C-in operand (shifted table, diag+1 slots are zero)
    f32x16 s;
#pragma unroll
    for (int g = 0; g < 4; ++g) {
      ushort4 bd4 = *(const ushort4*)&Wl[l31][m0 + 8 * g + 4 * hi];
      s[4 * g + 0] = bf2f(bd4.x);
      s[4 * g + 1] = bf2f(bd4.y);
      s[4 * g + 2] = bf2f(bd4.z);
      s[4 * g + 3] = bf2f(bd4.w);
    }
    s = MF32(kc0, qb0, s);
    s = MF32(kc1, qb1, s);
    s = MF32(kc2, qb2, s);
    s = MF32(kc3, qb3, s);
    // prefetch NEXT chunk's K during the exp2/pack phase
    if (ci < 3) {
      const unsigned short* kn = KTb + (size_t)(mt + 8) * 2048 + l * 8;
      kc0 = *(const short8*)(kn);
      kc1 = *(const short8*)(kn + 512);
      kc2 = *(const short8*)(kn + 1024);
      kc3 = *(const short8*)(kn + 1536);
    }
    float sum = 0.f;
#pragma unroll
    for (int i2 = 0; i2 < 16; ++i2) { s[i2] = EXP2(s[i2]); sum += s[i2]; }
    sum += __shfl_xor(sum, 32);
    run_l += sum;
    // PV B-frags: lane's own s in-order (V rows pre-permuted by sigma in vt_addr)
    short8 bp0, bp1;
    {
      unsigned int* u = (unsigned int*)&bp0;
      u[0] = cvt_pk_bf16(s[0], s[1]);
      u[1] = cvt_pk_bf16(s[2], s[3]);
      u[2] = cvt_pk_bf16(s[4], s[5]);
      u[3] = cvt_pk_bf16(s[6], s[7]);
      unsigned int* v2 = (unsigned int*)&bp1;
      v2[0] = cvt_pk_bf16(s[8], s[9]);
      v2[1] = cvt_pk_bf16(s[10], s[11]);
      v2[2] = cvt_pk_bf16(s[12], s[13]);
      v2[3] = cvt_pk_bf16(s[14], s[15]);
    }
    Oa0 = MF32(vv0, bp0, Oa0);
    Oa0 = MF32(vv1, bp1, Oa0);
    Oa1 = MF32(vv2, bp0, Oa1);
    Oa1 = MF32(vv3, bp1, Oa1);
  }

  __syncthreads();
  float* WLf = (float*)&Wl[0][0];
  float* myO = WLf + w * 2176;
#pragma unroll
  for (int i2 = 0; i2 < 16; ++i2) {
    int o0 = (i2 & 3) + 8 * (i2 >> 2) + 4 * hi;
    myO[o0 * 33 + l31]        = Oa0[i2];
    myO[(o0 + 32) * 33 + l31] = Oa1[i2];
  }
  if (l < 32) myO[2112 + l] = run_l;
  __syncthreads();
#pragma unroll
  for (int q4 = 0; q4 < 4; ++q4) {
    int q = w * 4 + q4;
    float denom = 0.f, val = 0.f;
#pragma unroll
    for (int w2 = 0; w2 < 8; ++w2) {
      denom += WLf[w2 * 2176 + 2112 + q];
      val   += WLf[w2 * 2176 + l * 33 + q];
    }
    pre[x16(b * TT + n0 + q, h * HS + l)] = f2bf(val / denom);
  }
}

extern "C" void kernel_launch(void* const* d_in, const int* in_sizes, int n_in,
                              void* d_out, int out_size, void* d_ws, size_t ws_size,
                              hipStream_t stream) {
  const float* inputs = (const float*)d_in[0];
  const float* pos    = (const float*)d_in[1];
  const float* gamma  = (const float*)d_in[2];
  const float* beta   = (const float*)d_in[3];
  const float* Wq = (const float*)d_in[4];
  const float* Wk = (const float*)d_in[5];
  const float* Wv = (const float*)d_in[6];
  const float* Wp = (const float*)d_in[7];
  const float* bu = (const float*)d_in[8];
  const float* bv = (const float*)d_in[9];
  const float* Wo = (const float*)d_in[10];
  const float* bo = (const float*)d_in[11];
  float* out = (float*)d_out;
  unsigned short* w16 = (unsigned short*)d_ws;

  const size_t T2 = (size_t)BB * TT * DD;
  unsigned short* x_bf  = w16;
  unsigned short* pre_b = x_bf  + T2;
  unsigned short* QUp   = pre_b + T2;
  unsigned short* QVp   = QUp   + T2;
  unsigned short* Kp    = QVp   + T2;
  unsigned short* Vtp   = Kp    + T2;
  unsigned short* Pp    = Vtp   + T2;
  unsigned short* Pos16 = Pp    + T2;
  unsigned short* WtQ   = Pos16 + T2;
  unsigned short* WtK   = WtQ + 262144;
  unsigned short* WtV   = WtK + 262144;
  unsigned short* WtP   = WtV + 262144;
  unsigned short* WoTT  = WtP + 262144;

  prep<<<dim3(512, 3), dim3(256), 0, stream>>>(inputs, pos, gamma, beta, Wq, Wk, Wv, Wp, Wo,
                                               x_bf, Pos16, WtQ, WtK, WtV, WtP, WoTT);
  proj2<<<dim3(16, 8, 4), dim3(512), 0, stream>>>(x_bf, Pos16, WtQ, WtK, WtV, WtP, bu, bv,
                                                  QUp, QVp, Kp, Vtp, Pp);
  attn_mfma<<<dim3(2048), dim3(512), 0, stream>>>(QUp, QVp, Kp, Vtp, Pp, pre_b);
  out2<<<dim3(32, 8), dim3(512), 0, stream>>>(pre_b, WoTT, inputs, bo, out);
}